// Round 9
// baseline (243.076 us; speedup 1.0000x reference)
//
#include <hip/hip_runtime.h>
#include <math.h>

// Problem constants (match reference)
#define BB 8
#define NN 2048
#define NCH 64
#define LN_EPS 1e-5f
#define BN (BB * NN)

typedef float f4 __attribute__((ext_vector_type(4)));

// ---------------------------------------------------------------------------
// Round 9: drop the fp16-A copy entirely. fp32 A (134 MB) fits in the 256 MB
// LLC, so pass 1 reads it with REGULAR (cache-allocating) loads and passes
// 2-3 re-read it from LLC. This removes the 64 MB A16 HBM writeback and all
// conversion stores, and makes every pass's dot pure fp32 (no half2 unpack).
// ---------------------------------------------------------------------------

// ---------------------------------------------------------------------------
// Kernel 1: P0[b,n] = sum_c X[b,n,c]. float4 loads, 16-lane-group reduce.
// ---------------------------------------------------------------------------
__global__ __launch_bounds__(256, 4) void xsum_kernel(
        const float* __restrict__ X, float* __restrict__ P) {
    const int tid = threadIdx.x;
    const int row = blockIdx.x * 16 + (tid >> 4);   // global row b*NN+n
    const int q   = tid & 15;
    float4 x = ((const float4*)X)[(size_t)row * 16 + q];
    float v = x.x + x.y + x.z + x.w;
    v += __shfl_xor(v, 8, 64);
    v += __shfl_xor(v, 4, 64);
    v += __shfl_xor(v, 2, 64);
    v += __shfl_xor(v, 1, 64);
    if (q == 0) P[row] = v;
}

// ---------------------------------------------------------------------------
// Kernel 2a: P1[b,m] = dot(A[b,m,:], P0[b,:]). fp32 A, REGULAR loads so A
// allocates in LLC for passes 2b/2c. 16 rows/block (4 waves x 4 rows),
// ping-pong register dbuf; first burst issued before LDS staging.
// Pure read-stream: only 16 KB of P1 stores total.
// ---------------------------------------------------------------------------
__global__ __launch_bounds__(256, 4) void matvec_kernel_a(
        const float* __restrict__ A,
        const float* __restrict__ pin,
        float* __restrict__ pout) {
    __shared__ float4 p4[NN / 4];       // 8 KB
    const int tid  = threadIdx.x;
    const int wave = tid >> 6;
    const int lane = tid & 63;
    const int b    = blockIdx.y;
    const int m0   = blockIdx.x * 16 + wave * 4;
    const float* Ab = A + (size_t)b * NN * NN;

    f4 buf[2][8];
    {   // issue first row's burst BEFORE LDS staging (latency overlap)
        const f4* r = (const f4*)(Ab + (size_t)m0 * NN);
        #pragma unroll
        for (int j = 0; j < 8; ++j)
            buf[0][j] = r[j * 64 + lane];
    }
    const float4* src = (const float4*)(pin + (size_t)b * NN);
    p4[tid]       = src[tid];
    p4[tid + 256] = src[tid + 256];
    __syncthreads();

    #pragma unroll
    for (int i = 0; i < 4; ++i) {
        const int m = m0 + i;
        if (i < 3) {   // issue next row before consuming current
            const f4* rn = (const f4*)(Ab + (size_t)(m + 1) * NN);
            #pragma unroll
            for (int j = 0; j < 8; ++j)
                buf[(i + 1) & 1][j] = rn[j * 64 + lane];
        }
        float acc = 0.f;
        #pragma unroll
        for (int j = 0; j < 8; ++j) {
            f4 x      = buf[i & 1][j];
            float4 pv = p4[j * 64 + lane];   // 16B lane stride: conflict-free
            acc += x.x * pv.x + x.y * pv.y + x.z * pv.z + x.w * pv.w;
        }
        #pragma unroll
        for (int off = 32; off > 0; off >>= 1)
            acc += __shfl_down(acc, off, 64);
        if (lane == 0) pout[(size_t)b * NN + m] = acc;
    }
}

// ---------------------------------------------------------------------------
// Kernel 2b: P2[b,m] = dot(A[b,m,:], P1[b,:]). A served from LLC.
// 8 rows/block (4 waves x 2 rows), BOTH rows fully prefetched (16 KB/wave
// in flight), loads issued before LDS staging. 2048 blocks for fine tail.
// ---------------------------------------------------------------------------
__global__ __launch_bounds__(256, 4) void matvec_kernel_b(
        const float* __restrict__ A,
        const float* __restrict__ pin,
        float* __restrict__ pout) {
    __shared__ float4 p4[NN / 4];       // 8 KB
    const int tid  = threadIdx.x;
    const int wave = tid >> 6;
    const int lane = tid & 63;
    const int b    = blockIdx.y;
    const int m0   = blockIdx.x * 8 + wave * 2;
    const float* Ab = A + (size_t)b * NN * NN;

    f4 buf[2][8];                        // both rows in flight (16 KB/wave)
    #pragma unroll
    for (int r = 0; r < 2; ++r) {
        const f4* rr = (const f4*)(Ab + (size_t)(m0 + r) * NN);
        #pragma unroll
        for (int j = 0; j < 8; ++j) buf[r][j] = rr[j * 64 + lane];
    }
    const float4* src = (const float4*)(pin + (size_t)b * NN);
    p4[tid]       = src[tid];
    p4[tid + 256] = src[tid + 256];
    __syncthreads();

    #pragma unroll
    for (int r = 0; r < 2; ++r) {
        const int m = m0 + r;
        float acc = 0.f;
        #pragma unroll
        for (int j = 0; j < 8; ++j) {
            f4 x      = buf[r][j];
            float4 pv = p4[j * 64 + lane];
            acc += x.x * pv.x + x.y * pv.y + x.z * pv.z + x.w * pv.w;
        }
        #pragma unroll
        for (int off = 32; off > 0; off >>= 1)
            acc += __shfl_down(acc, off, 64);
        if (lane == 0) pout[(size_t)b * NN + m] = acc;
    }
}

// ---------------------------------------------------------------------------
// Kernel 2c: P3 = A @ P2 fused with combine + LayerNorm + tanh. A from LLC.
// 8 rows/block; h tile staged through LDS transposed (hs[node][ch][term],
// 16B lane-stride reads); out store nontemporal (never re-read).
// ---------------------------------------------------------------------------
__global__ __launch_bounds__(256, 4) void matvec_ln_kernel(
        const float* __restrict__ A,
        const float* __restrict__ P,      // [3][B*N]  (P0, P1, P2)
        const float* __restrict__ h,      // [4, 64, NN]
        const float* __restrict__ gamma,  // [64]
        const float* __restrict__ beta,   // [64]
        float* __restrict__ out) {        // [BB, NN, 64]
    __shared__ float4 p4[NN / 4];        // 8 KB : P2 vector
    __shared__ float  hs[8][NCH][4];     // 8 KB : h tile [node][ch][term]
    const int tid  = threadIdx.x;
    const int wave = tid >> 6;
    const int lane = tid & 63;
    const int b    = blockIdx.y;
    const int bx   = blockIdx.x;
    const int m0   = bx * 8 + wave * 2;
    const float* Ab = A + (size_t)b * NN * NN;

    f4 buf[2][8];                        // both rows in flight
    #pragma unroll
    for (int r = 0; r < 2; ++r) {
        const f4* rr = (const f4*)(Ab + (size_t)(m0 + r) * NN);
        #pragma unroll
        for (int j = 0; j < 8; ++j) buf[r][j] = rr[j * 64 + lane];
    }

    {   // stage P2 vector
        const float4* src = (const float4*)(P + (size_t)(2 * BB + b) * NN);
        p4[tid]       = src[tid];
        p4[tid + 256] = src[tid + 256];
    }
    {   // stage h tile: thread (term=wave, ch=lane) loads h[wave][lane][bx*8..+8)
        const float4* hr =
            (const float4*)(h + ((size_t)(wave * NCH + lane)) * NN + bx * 8);
        #pragma unroll
        for (int k = 0; k < 2; ++k) {
            float4 hv = hr[k];
            hs[k * 4 + 0][lane][wave] = hv.x;
            hs[k * 4 + 1][lane][wave] = hv.y;
            hs[k * 4 + 2][lane][wave] = hv.z;
            hs[k * 4 + 3][lane][wave] = hv.w;
        }
    }
    __syncthreads();

    const float g  = gamma[lane];
    const float be = beta[lane];

    #pragma unroll
    for (int r = 0; r < 2; ++r) {
        const int m   = m0 + r;
        const int idx = b * NN + m;
        const float p0 = P[idx];          // issue early, consumed after dot
        const float p1 = P[BN + idx];

        float acc = 0.f;
        #pragma unroll
        for (int j = 0; j < 8; ++j) {
            f4 x      = buf[r][j];
            float4 pv = p4[j * 64 + lane];
            acc += x.x * pv.x + x.y * pv.y + x.z * pv.z + x.w * pv.w;
        }
        #pragma unroll
        for (int off = 32; off > 0; off >>= 1)   // all lanes need p3
            acc += __shfl_xor(acc, off, 64);
        const float p3 = acc;
        const float p2 = ((const float*)p4)[m];  // P2 from LDS

        const int  node = wave * 2 + r;          // node index within block tile
        const float4 hv = *(const float4*)&hs[node][lane][0];
        float y = hv.x * p0 + hv.y * p1 + hv.z * p2 + hv.w * p3;

        float sum = y;
        #pragma unroll
        for (int off = 32; off > 0; off >>= 1)
            sum += __shfl_xor(sum, off, 64);
        const float mean = sum * (1.f / NCH);

        float d  = y - mean;
        float vs = d * d;
        #pragma unroll
        for (int off = 32; off > 0; off >>= 1)
            vs += __shfl_xor(vs, off, 64);
        const float rstd = rsqrtf(vs * (1.f / NCH) + LN_EPS);

        __builtin_nontemporal_store(
            tanhf(d * rstd * g + be),
            &out[(size_t)idx * NCH + lane]);
    }
}

// ---------------------------------------------------------------------------
extern "C" void kernel_launch(void* const* d_in, const int* in_sizes, int n_in,
                              void* d_out, int out_size, void* d_ws, size_t ws_size,
                              hipStream_t stream) {
    const float* A     = (const float*)d_in[0];  // [B, N, N]
    const float* X     = (const float*)d_in[1];  // [B, N, 64]
    const float* h     = (const float*)d_in[2];  // [4, 64, N]
    const float* gamma = (const float*)d_in[3];  // [64]
    const float* beta  = (const float*)d_in[4];  // [64]
    float* out = (float*)d_out;                  // [B, N, 64]

    // workspace layout: P[3][B*N] floats (192 KB); no A16 copy anymore
    float* P = (float*)d_ws;

    // 1) P0 = rowsum(X)
    xsum_kernel<<<dim3(BN / 16), dim3(256), 0, stream>>>(X, P);

    // 2) P1 = A @ P0   (regular loads -> A allocates in the 256 MB LLC)
    matvec_kernel_a<<<dim3(NN / 16, BB), dim3(256), 0, stream>>>(
        A, P, P + BN);

    // 3) P2 = A @ P1   (A from LLC)
    matvec_kernel_b<<<dim3(NN / 8, BB), dim3(256), 0, stream>>>(
        A, P + BN, P + 2 * BN);

    // 4) P3 = A @ P2, fused with combine + LayerNorm + tanh (A from LLC)
    matvec_ln_kernel<<<dim3(NN / 8, BB), dim3(256), 0, stream>>>(
        A, P, h, gamma, beta, out);
}

// Round 10
// 225.753 us; speedup vs baseline: 1.0767x; 1.0767x over previous
//
#include <hip/hip_runtime.h>
#include <hip/hip_fp16.h>
#include <math.h>

// Problem constants (match reference)
#define BB 8
#define NN 2048
#define NCH 64
#define LN_EPS 1e-5f
#define BN (BB * NN)

typedef float f4 __attribute__((ext_vector_type(4)));

// ---------------------------------------------------------------------------
// BEST CONFIG (round 8, 226.7 us): 4-kernel split, fp16 A-copy resident in
// LLC for passes 2b/2c, h staged via LDS transposed, de-interleaved p LDS.
// Reverted from round 9 (fp32-from-LLC, 243 us): doubling LLC-read volume
// (134 MB/pass vs 67 MB) cost more than the 64 MB A16 writeback saved.
// ---------------------------------------------------------------------------

// ---------------------------------------------------------------------------
// Kernel 1: P0[b,n] = sum_c X[b,n,c]. float4 loads, 16-lane-group reduce,
// 16 rows/block, 1024 blocks.
// ---------------------------------------------------------------------------
__global__ __launch_bounds__(256, 4) void xsum_kernel(
        const float* __restrict__ X, float* __restrict__ P) {
    const int tid = threadIdx.x;
    const int row = blockIdx.x * 16 + (tid >> 4);   // global row b*NN+n
    const int q   = tid & 15;
    float4 x = ((const float4*)X)[(size_t)row * 16 + q];
    float v = x.x + x.y + x.z + x.w;
    v += __shfl_xor(v, 8, 64);
    v += __shfl_xor(v, 4, 64);
    v += __shfl_xor(v, 2, 64);
    v += __shfl_xor(v, 1, 64);
    if (q == 0) P[row] = v;
}

// ---------------------------------------------------------------------------
// Kernel 2a: P1[b,m] = dot(A[b,m,:], P0[b,:]) (fp32 A, NONTEMPORAL: streamed,
// no LLC allocation) AND A16[b,m,:] = fp16(A[b,m,:]) via REGULAR stores so
// the fp16 copy drains to LLC -> passes 2b/2c read it from LLC, not HBM.
// 16 rows/block (4 waves x 4 rows), ping-pong register dbuf.
// ---------------------------------------------------------------------------
__global__ __launch_bounds__(256, 4) void matvec_cvt_kernel(
        const float* __restrict__ A,
        const float* __restrict__ pin,
        float* __restrict__ pout,
        __half* __restrict__ A16) {
    __shared__ float4 p4[NN / 4];       // 8 KB
    const int tid  = threadIdx.x;
    const int wave = tid >> 6;
    const int lane = tid & 63;
    const int b    = blockIdx.y;
    const int m0   = blockIdx.x * 16 + wave * 4;
    const float* Ab = A + (size_t)b * NN * NN;

    f4 buf[2][8];
    {   // issue first row's burst BEFORE LDS staging (latency overlap)
        const f4* r = (const f4*)(Ab + (size_t)m0 * NN);
        #pragma unroll
        for (int j = 0; j < 8; ++j)
            buf[0][j] = __builtin_nontemporal_load(&r[j * 64 + lane]);
    }
    const float4* src = (const float4*)(pin + (size_t)b * NN);
    p4[tid]       = src[tid];
    p4[tid + 256] = src[tid + 256];
    __syncthreads();

    #pragma unroll
    for (int i = 0; i < 4; ++i) {
        const int m = m0 + i;
        if (i < 3) {   // issue next row before consuming current
            const f4* rn = (const f4*)(Ab + (size_t)(m + 1) * NN);
            #pragma unroll
            for (int j = 0; j < 8; ++j)
                buf[(i + 1) & 1][j] = __builtin_nontemporal_load(&rn[j * 64 + lane]);
        }
        float acc = 0.f;
        #pragma unroll
        for (int j = 0; j < 8; ++j) {
            f4 x      = buf[i & 1][j];
            float4 pv = p4[j * 64 + lane];
            acc += x.x * pv.x + x.y * pv.y + x.z * pv.z + x.w * pv.w;
        }
        float2* A16r = (float2*)(A16 + (size_t)b * NN * NN + (size_t)m * NN);
        #pragma unroll
        for (int j = 0; j < 8; ++j) {
            union { float2 f2; __half2 h2[2]; } u;
            u.h2[0] = __floats2half2_rn(buf[i & 1][j].x, buf[i & 1][j].y);
            u.h2[1] = __floats2half2_rn(buf[i & 1][j].z, buf[i & 1][j].w);
            A16r[j * 64 + lane] = u.f2;
        }
        #pragma unroll
        for (int off = 32; off > 0; off >>= 1)
            acc += __shfl_down(acc, off, 64);
        if (lane == 0) pout[(size_t)b * NN + m] = acc;
    }
}

// ---------------------------------------------------------------------------
// Kernel 2b: P2[b,m] = dot(A16[b,m,:], P1[b,:]). LLC-served A16.
// p vector stored DE-INTERLEAVED into pA/pB: dot reads at 16B lane stride
// (2 lanes/bank = free) instead of 32B stride (~16-way conflict).
// ---------------------------------------------------------------------------
__global__ __launch_bounds__(256, 8) void matvec16_kernel(
        const __half* __restrict__ A16,
        const float* __restrict__ pin,
        float* __restrict__ pout) {
    __shared__ float4 pA[NN / 8];       // 4 KB : p[8k..8k+4)
    __shared__ float4 pB[NN / 8];       // 4 KB : p[8k+4..8k+8)
    const int tid  = threadIdx.x;
    const int wave = tid >> 6;
    const int lane = tid & 63;
    const int b    = blockIdx.y;
    const int m0   = blockIdx.x * 8 + wave * 2;
    const __half* Ab = A16 + (size_t)b * NN * NN;

    float4 buf[2][4];                    // both rows in flight (8 KB/wave)
    #pragma unroll
    for (int r = 0; r < 2; ++r) {
        const float4* rr = (const float4*)(Ab + (size_t)(m0 + r) * NN);
        #pragma unroll
        for (int j = 0; j < 4; ++j) buf[r][j] = rr[j * 64 + lane];
    }
    {   // de-interleaved staging: thread t reads 32B contiguous (coalesced)
        const float4* src = (const float4*)(pin + (size_t)b * NN);
        pA[tid] = src[2 * tid];
        pB[tid] = src[2 * tid + 1];
    }
    __syncthreads();

    #pragma unroll
    for (int r = 0; r < 2; ++r) {
        const int m = m0 + r;
        float acc = 0.f;
        #pragma unroll
        for (int j = 0; j < 4; ++j) {
            float4 pa = pA[j * 64 + lane];   // 16B lane stride: conflict-free
            float4 pb = pB[j * 64 + lane];
            const __half2* hx = (const __half2*)&buf[r][j];
            float2 f0 = __half22float2(hx[0]);
            float2 f1 = __half22float2(hx[1]);
            float2 f2 = __half22float2(hx[2]);
            float2 f3 = __half22float2(hx[3]);
            acc += f0.x * pa.x + f0.y * pa.y + f1.x * pa.z + f1.y * pa.w
                 + f2.x * pb.x + f2.y * pb.y + f3.x * pb.z + f3.y * pb.w;
        }
        #pragma unroll
        for (int off = 32; off > 0; off >>= 1)
            acc += __shfl_down(acc, off, 64);
        if (lane == 0) pout[(size_t)b * NN + m] = acc;
    }
}

// ---------------------------------------------------------------------------
// Kernel 2c: P3 = A16 @ P2 fused with combine + LayerNorm + tanh.
// Same de-interleaved pA/pB as 2b. h tile staged through LDS transposed
// (hs[node][ch][term], 16B lane stride reads). out store nontemporal.
// ---------------------------------------------------------------------------
__global__ __launch_bounds__(256, 4) void matvec16_ln_kernel(
        const __half* __restrict__ A16,
        const float* __restrict__ P,      // [3][B*N]  (P0, P1, P2)
        const float* __restrict__ h,      // [4, 64, NN]
        const float* __restrict__ gamma,  // [64]
        const float* __restrict__ beta,   // [64]
        float* __restrict__ out) {        // [BB, NN, 64]
    __shared__ float4 pA[NN / 8];        // 4 KB
    __shared__ float4 pB[NN / 8];        // 4 KB
    __shared__ float  hs[8][NCH][4];     // 8 KB : h tile [node][ch][term]
    const int tid  = threadIdx.x;
    const int wave = tid >> 6;
    const int lane = tid & 63;
    const int b    = blockIdx.y;
    const int bx   = blockIdx.x;
    const int m0   = bx * 8 + wave * 2;
    const __half* Ab = A16 + (size_t)b * NN * NN;

    float4 buf[2][4];                    // both rows in flight
    #pragma unroll
    for (int r = 0; r < 2; ++r) {
        const float4* rr = (const float4*)(Ab + (size_t)(m0 + r) * NN);
        #pragma unroll
        for (int j = 0; j < 4; ++j) buf[r][j] = rr[j * 64 + lane];
    }

    {   // stage P2 vector (de-interleaved)
        const float4* src = (const float4*)(P + (size_t)(2 * BB + b) * NN);
        pA[tid] = src[2 * tid];
        pB[tid] = src[2 * tid + 1];
    }
    {   // stage h tile: thread (term=wave, ch=lane) loads h[wave][lane][bx*8..+8)
        const float4* hr =
            (const float4*)(h + ((size_t)(wave * NCH + lane)) * NN + bx * 8);
        #pragma unroll
        for (int k = 0; k < 2; ++k) {
            float4 hv = hr[k];
            hs[k * 4 + 0][lane][wave] = hv.x;
            hs[k * 4 + 1][lane][wave] = hv.y;
            hs[k * 4 + 2][lane][wave] = hv.z;
            hs[k * 4 + 3][lane][wave] = hv.w;
        }
    }
    __syncthreads();

    const float g  = gamma[lane];
    const float be = beta[lane];

    #pragma unroll
    for (int r = 0; r < 2; ++r) {
        const int m   = m0 + r;
        const int idx = b * NN + m;
        const float p0 = P[idx];          // issue early, consumed after dot
        const float p1 = P[BN + idx];

        float acc = 0.f;
        #pragma unroll
        for (int j = 0; j < 4; ++j) {
            float4 pa = pA[j * 64 + lane];   // conflict-free
            float4 pb = pB[j * 64 + lane];
            const __half2* hx = (const __half2*)&buf[r][j];
            float2 f0 = __half22float2(hx[0]);
            float2 f1 = __half22float2(hx[1]);
            float2 f2 = __half22float2(hx[2]);
            float2 f3 = __half22float2(hx[3]);
            acc += f0.x * pa.x + f0.y * pa.y + f1.x * pa.z + f1.y * pa.w
                 + f2.x * pb.x + f2.y * pb.y + f3.x * pb.z + f3.y * pb.w;
        }
        #pragma unroll
        for (int off = 32; off > 0; off >>= 1)   // all lanes need p3
            acc += __shfl_xor(acc, off, 64);
        const float p3 = acc;
        // P2 element m from split LDS: array chosen by bit 2 of m.
        const float* pp = ((m >> 2) & 1) ? (const float*)pB : (const float*)pA;
        const float p2  = pp[((m >> 3) << 2) | (m & 3)];

        const int  node = wave * 2 + r;          // node index within block tile
        const float4 hv = *(const float4*)&hs[node][lane][0];
        float y = hv.x * p0 + hv.y * p1 + hv.z * p2 + hv.w * p3;

        float sum = y;
        #pragma unroll
        for (int off = 32; off > 0; off >>= 1)
            sum += __shfl_xor(sum, off, 64);
        const float mean = sum * (1.f / NCH);

        float d  = y - mean;
        float vs = d * d;
        #pragma unroll
        for (int off = 32; off > 0; off >>= 1)
            vs += __shfl_xor(vs, off, 64);
        const float rstd = rsqrtf(vs * (1.f / NCH) + LN_EPS);

        __builtin_nontemporal_store(
            tanhf(d * rstd * g + be),
            &out[(size_t)idx * NCH + lane]);
    }
}

// ---------------------------------------------------------------------------
extern "C" void kernel_launch(void* const* d_in, const int* in_sizes, int n_in,
                              void* d_out, int out_size, void* d_ws, size_t ws_size,
                              hipStream_t stream) {
    const float* A     = (const float*)d_in[0];  // [B, N, N]
    const float* X     = (const float*)d_in[1];  // [B, N, 64]
    const float* h     = (const float*)d_in[2];  // [4, 64, N]
    const float* gamma = (const float*)d_in[3];  // [64]
    const float* beta  = (const float*)d_in[4];  // [64]
    float* out = (float*)d_out;                  // [B, N, 64]

    // workspace layout: P[3][B*N] floats (192 KB), A16 at +1 MB (64 MB)
    float*  P   = (float*)d_ws;
    __half* A16 = (__half*)((char*)d_ws + (1u << 20));

    // 1) P0 = rowsum(X)
    xsum_kernel<<<dim3(BN / 16), dim3(256), 0, stream>>>(X, P);

    // 2) P1 = A @ P0  (fp32 A nontemporal, emits fp16 copy of A into LLC)
    matvec_cvt_kernel<<<dim3(NN / 16, BB), dim3(256), 0, stream>>>(
        A, P, P + BN, A16);

    // 3) P2 = A16 @ P1
    matvec16_kernel<<<dim3(NN / 8, BB), dim3(256), 0, stream>>>(
        A16, P + BN, P + 2 * BN);

    // 4) P3 = A16 @ P2, fused with combine + LayerNorm + tanh
    matvec16_ln_kernel<<<dim3(NN / 8, BB), dim3(256), 0, stream>>>(
        A16, P, h, gamma, beta, out);
}